// Round 4
// baseline (88.394 us; speedup 1.0000x reference)
//
#include <hip/hip_runtime.h>

#define NUM_HASHES 4
#define DIM 256

typedef float v4f __attribute__((ext_vector_type(4)));

// Grid-stride, one wave (64 lanes) per position per iteration; lane i owns
// floats [4i,4i+4). Tables (8 KB + 263 KB) are L2-resident; kernel is bound
// by the 64 MiB write-once output. This round's single variable: plain
// (through-L2) store instead of __builtin_nontemporal_store, to A/B whether
// the nt flag throttles streaming write BW vs the ~5.9 TB/s the harness
// fills achieve through L2.
__global__ __launch_bounds__(256) void HashEmbedding_44976897523736_kernel(
    const int* __restrict__ x,          // [num_pos, 4] int32
    const float* __restrict__ wt,       // [2052]
    const float* __restrict__ emb,      // [257, 256]
    float* __restrict__ out,            // [num_pos, 256]
    int num_pos, int num_waves)
{
    const int lane = threadIdx.x & 63;
    const int wave = blockIdx.x * (blockDim.x >> 6) + (threadIdx.x >> 6);

    #pragma unroll 2
    for (int p = wave; p < num_pos; p += num_waves) {
        const int4 xi = *reinterpret_cast<const int4*>(x + p * NUM_HASHES);

        const float w0 = wt[xi.x];
        const float w1 = wt[xi.y + 513];
        const float w2 = wt[xi.z + 1026];
        const float w3 = wt[xi.w + 1539];

        const v4f e0 = reinterpret_cast<const v4f*>(emb + (xi.x >> 1) * DIM)[lane];
        const v4f e1 = reinterpret_cast<const v4f*>(emb + (xi.y >> 1) * DIM)[lane];
        const v4f e2 = reinterpret_cast<const v4f*>(emb + (xi.z >> 1) * DIM)[lane];
        const v4f e3 = reinterpret_cast<const v4f*>(emb + (xi.w >> 1) * DIM)[lane];

        v4f r = w0 * e0 + w1 * e1 + w2 * e2 + w3 * e3;

        *(reinterpret_cast<v4f*>(out + (size_t)p * DIM) + lane) = r;
    }
}

extern "C" void kernel_launch(void* const* d_in, const int* in_sizes, int n_in,
                              void* d_out, int out_size, void* d_ws, size_t ws_size,
                              hipStream_t stream) {
    const int*   x   = (const int*)d_in[0];
    const float* wt  = (const float*)d_in[1];
    const float* emb = (const float*)d_in[2];
    float*       out = (float*)d_out;

    const int num_pos = in_sizes[0] / NUM_HASHES;   // 65536

    // 2048 blocks x 4 waves = 8192 waves (8/SIMD across 256 CUs),
    // 8 grid-stride iterations/wave at num_pos=65536.
    const int block = 256;
    int blocks = 2048;
    int num_waves = blocks * (block / 64);
    if (num_waves > num_pos) {                      // tiny-input fallback
        blocks = (num_pos + (block / 64) - 1) / (block / 64);
        if (blocks < 1) blocks = 1;
        num_waves = blocks * (block / 64);
    }

    HashEmbedding_44976897523736_kernel<<<blocks, block, 0, stream>>>(
        x, wt, emb, out, num_pos, num_waves);
}